// Round 1
// baseline (3448.578 us; speedup 1.0000x reference)
//
#include <hip/hip_runtime.h>

#define TSEQ 2048
#define DM   768
#define NH   12
#define NKV  4
#define HD   64
#define FFD  2048
#define NL   4
#define VOC  32000
#define QKVN 1280   // 768 q + 256 k + 256 v

typedef __attribute__((ext_vector_type(8))) short short8;
typedef __attribute__((ext_vector_type(4))) float f32x4;

__device__ __forceinline__ unsigned short f2b(float f) {
  unsigned int u = __float_as_uint(f);
  u += 0x7fffu + ((u >> 16) & 1u);
  return (unsigned short)(u >> 16);
}
__device__ __forceinline__ float b2f(unsigned short u) {
  return __uint_as_float(((unsigned int)u) << 16);
}
__device__ __forceinline__ unsigned int packbf(float a, float b) {
  return (unsigned int)f2b(a) | ((unsigned int)f2b(b) << 16);
}
__device__ __forceinline__ void unp8(uint4 u, float* o) {
  o[0] = __uint_as_float(u.x << 16); o[1] = __uint_as_float(u.x & 0xffff0000u);
  o[2] = __uint_as_float(u.y << 16); o[3] = __uint_as_float(u.y & 0xffff0000u);
  o[4] = __uint_as_float(u.z << 16); o[5] = __uint_as_float(u.z & 0xffff0000u);
  o[6] = __uint_as_float(u.w << 16); o[7] = __uint_as_float(u.w & 0xffff0000u);
}
__device__ __forceinline__ float dot4(float4 a, float4 b) {
  return a.x*b.x + a.y*b.y + a.z*b.z + a.w*b.w;
}

// ---------------- cast f32 -> bf16 (vectorized x4) ----------------
__global__ void cast_bf16_kernel(const float* __restrict__ src,
                                 unsigned short* __restrict__ dst, int n4) {
  int i = blockIdx.x * blockDim.x + threadIdx.x;
  if (i >= n4) return;
  float4 v = ((const float4*)src)[i];
  uint2 o; o.x = packbf(v.x, v.y); o.y = packbf(v.z, v.w);
  ((uint2*)dst)[i] = o;
}

// ---------------- transpose + cast: src [K][N] f32 -> dst [N][K] bf16 ----------------
__global__ void transpose_cast_kernel(const float* __restrict__ src,
                                      unsigned short* __restrict__ dst,
                                      int K, int N) {
  __shared__ float tile[32][33];
  int n0 = blockIdx.x * 32, k0 = blockIdx.y * 32;
  int tx = threadIdx.x, ty = threadIdx.y;  // 32 x 8
  #pragma unroll
  for (int i = 0; i < 4; ++i) {
    int r = ty + i * 8;
    tile[r][tx] = src[(size_t)(k0 + r) * N + n0 + tx];
  }
  __syncthreads();
  #pragma unroll
  for (int i = 0; i < 4; ++i) {
    int r = ty + i * 8;
    dst[(size_t)(n0 + r) * K + k0 + tx] = f2b(tile[tx][r]);
  }
}

// ---------------- embedding gather ----------------
__global__ void gather_kernel(const int* __restrict__ idx,
                              const float* __restrict__ embed,
                              float* __restrict__ x) {
  int row = blockIdx.x; int t = threadIdx.x;  // 192 threads, float4 each
  int id = idx[row];
  ((float4*)(x + (size_t)row * DM))[t] = ((const float4*)(embed + (size_t)id * DM))[t];
}

// ---------------- RMSNorm: f32 in -> bf16 out ----------------
__global__ void rmsnorm_kernel(const float* __restrict__ x,
                               const float* __restrict__ w,
                               unsigned short* __restrict__ out) {
  int row = blockIdx.x; int t = threadIdx.x;  // 256 threads, D=768
  const float* xr = x + (size_t)row * DM;
  float v0 = xr[t], v1 = xr[t + 256], v2 = xr[t + 512];
  float s = v0*v0 + v1*v1 + v2*v2;
  #pragma unroll
  for (int off = 1; off < 64; off <<= 1) s += __shfl_xor(s, off);
  __shared__ float red[4];
  if ((t & 63) == 0) red[t >> 6] = s;
  __syncthreads();
  float tot = red[0] + red[1] + red[2] + red[3];
  float rs = rsqrtf(tot * (1.0f / DM) + 1e-6f);
  unsigned short* orow = out + (size_t)row * DM;
  orow[t]       = f2b(w[t]       * v0 * rs);
  orow[t + 256] = f2b(w[t + 256] * v1 * rs);
  orow[t + 512] = f2b(w[t + 512] * v2 * rs);
}

// ---------------- RoPE in-place on q (cols 0..767, 12 heads) and k (768..1023, 4 heads) ----------------
__global__ void rope_kernel(unsigned short* __restrict__ qkv) {
  int pos = blockIdx.x; int t = threadIdx.x;
  int head = t >> 4;        // 0..15 (12 q heads + 4 k heads)
  int pi = t & 15;
  int base = (head < NH) ? head * HD : DM + (head - NH) * HD;
  unsigned short* row = qkv + (size_t)pos * QKVN + base;
  #pragma unroll
  for (int pp = 0; pp < 2; ++pp) {
    int i = pi * 2 + pp;  // 0..31
    // inv_freq = 10000^(-i/32) = 2^(-i * log2(10000)/32)
    float inv = exp2f(-(float)i * (13.287712379549449f / 32.0f));
    float ang = (float)pos * inv;
    float sv, cv; sincosf(ang, &sv, &cv);
    float x1 = b2f(row[i]), x2 = b2f(row[i + 32]);
    row[i]      = f2b(x1 * cv - x2 * sv);
    row[i + 32] = f2b(x2 * cv + x1 * sv);
  }
}

// ---------------- GEMM: C[M][N] = A[M][K] @ Bt[N][K]^T ----------------
// OUT: 0 = f32 store, 1 = f32 +=, 2 = bf16 store
template <int OUT>
__global__ __launch_bounds__(256) void gemm_bt_kernel(
    const unsigned short* __restrict__ A, const unsigned short* __restrict__ Bt,
    void* __restrict__ Cv, int N, int K) {
  __shared__ unsigned short As[128 * 40];
  __shared__ unsigned short Bs[128 * 40];
  int tid = threadIdx.x;
  int m0 = blockIdx.y * 128, n0 = blockIdx.x * 128;
  int lane = tid & 63, wave = tid >> 6;
  int wr = (wave >> 1) * 64, wc = (wave & 1) * 64;
  int l16 = lane & 15, lk8 = (lane >> 4) * 8;
  f32x4 acc[4][4];
  #pragma unroll
  for (int m = 0; m < 4; ++m)
    #pragma unroll
    for (int n = 0; n < 4; ++n) acc[m][n] = (f32x4){0.f, 0.f, 0.f, 0.f};
  const unsigned short* Abase = A + (size_t)m0 * K;
  const unsigned short* Bbase = Bt + (size_t)n0 * K;
  int r0 = tid >> 2;            // 0..63
  int c0 = (tid & 3) * 8;       // 0,8,16,24
  for (int k0 = 0; k0 < K; k0 += 32) {
    uint4 a0 = *(const uint4*)(Abase + (size_t)r0 * K + k0 + c0);
    uint4 a1 = *(const uint4*)(Abase + (size_t)(r0 + 64) * K + k0 + c0);
    uint4 b0 = *(const uint4*)(Bbase + (size_t)r0 * K + k0 + c0);
    uint4 b1 = *(const uint4*)(Bbase + (size_t)(r0 + 64) * K + k0 + c0);
    *(uint4*)&As[r0 * 40 + c0] = a0;
    *(uint4*)&As[(r0 + 64) * 40 + c0] = a1;
    *(uint4*)&Bs[r0 * 40 + c0] = b0;
    *(uint4*)&Bs[(r0 + 64) * 40 + c0] = b1;
    __syncthreads();
    short8 af[4], bfr[4];
    #pragma unroll
    for (int m = 0; m < 4; ++m) af[m]  = *(const short8*)&As[(wr + m*16 + l16) * 40 + lk8];
    #pragma unroll
    for (int n = 0; n < 4; ++n) bfr[n] = *(const short8*)&Bs[(wc + n*16 + l16) * 40 + lk8];
    #pragma unroll
    for (int m = 0; m < 4; ++m)
      #pragma unroll
      for (int n = 0; n < 4; ++n)
        acc[m][n] = __builtin_amdgcn_mfma_f32_16x16x32_bf16(af[m], bfr[n], acc[m][n], 0, 0, 0);
    __syncthreads();
  }
  // C/D layout: col = lane&15, row = (lane>>4)*4 + reg   [learn_hip m89/m91]
  if (OUT == 2) {
    unsigned short* C = (unsigned short*)Cv;
    #pragma unroll
    for (int m = 0; m < 4; ++m)
      #pragma unroll
      for (int r = 0; r < 4; ++r) {
        size_t row = (size_t)(m0 + wr + m*16 + ((lane >> 4) << 2) + r);
        unsigned short* Cr = C + row * N + n0 + wc + l16;
        #pragma unroll
        for (int n = 0; n < 4; ++n) Cr[n * 16] = f2b(acc[m][n][r]);
      }
  } else {
    float* C = (float*)Cv;
    #pragma unroll
    for (int m = 0; m < 4; ++m)
      #pragma unroll
      for (int r = 0; r < 4; ++r) {
        size_t row = (size_t)(m0 + wr + m*16 + ((lane >> 4) << 2) + r);
        float* Cr = C + row * N + n0 + wc + l16;
        #pragma unroll
        for (int n = 0; n < 4; ++n) {
          if (OUT == 1) Cr[n * 16] += acc[m][n][r];
          else          Cr[n * 16]  = acc[m][n][r];
        }
      }
  }
}

// ---------------- flash attention (f32 VALU), causal, GQA ----------------
__global__ __launch_bounds__(256) void attn_kernel(const unsigned short* __restrict__ qkv,
                                                   unsigned short* __restrict__ out) {
  __shared__ float kl[64][64];
  __shared__ float vl[64][64];
  int h = blockIdx.y;
  int r0 = blockIdx.x * 64;
  int t = threadIdx.x;
  int rr = t >> 2;           // query row within tile
  int d0 = (t & 3) * 16;     // dim slice
  int row = r0 + rr;
  int kvh = h / 3;           // N_REP = 3
  float q[16];
  {
    const uint4* qp = (const uint4*)(qkv + (size_t)row * QKVN + h * HD + d0);
    uint4 u0 = qp[0], u1 = qp[1];
    unp8(u0, q); unp8(u1, q + 8);
    #pragma unroll
    for (int i = 0; i < 16; ++i) q[i] *= 0.125f;  // 1/sqrt(64)
  }
  float4 q4[4];
  #pragma unroll
  for (int i = 0; i < 4; ++i) q4[i] = make_float4(q[4*i], q[4*i+1], q[4*i+2], q[4*i+3]);
  float mrun = -1e30f, lrun = 0.0f;
  float4 av[4];
  #pragma unroll
  for (int i = 0; i < 4; ++i) av[i] = make_float4(0.f, 0.f, 0.f, 0.f);
  int nt = blockIdx.x + 1;
  for (int kt = 0; kt < nt; ++kt) {
    int kb = kt * 64;
    __syncthreads();
    {
      const unsigned short* krow = qkv + (size_t)(kb + rr) * QKVN + DM + kvh * HD + d0;
      const unsigned short* vrow = qkv + (size_t)(kb + rr) * QKVN + DM + NKV * HD + kvh * HD + d0;
      uint4 a0 = ((const uint4*)krow)[0], a1 = ((const uint4*)krow)[1];
      uint4 b0 = ((const uint4*)vrow)[0], b1 = ((const uint4*)vrow)[1];
      unp8(a0, &kl[rr][d0]); unp8(a1, &kl[rr][d0 + 8]);
      unp8(b0, &vl[rr][d0]); unp8(b1, &vl[rr][d0 + 8]);
    }
    __syncthreads();
    int kmax = row - kb + 1; if (kmax > 64) kmax = 64;
    for (int j = 0; j < kmax; ++j) {
      const float4* kj = (const float4*)&kl[j][d0];
      float s = dot4(q4[0], kj[0]) + dot4(q4[1], kj[1]) + dot4(q4[2], kj[2]) + dot4(q4[3], kj[3]);
      s += __shfl_xor(s, 1);
      s += __shfl_xor(s, 2);
      const float4* vj = (const float4*)&vl[j][d0];
      if (s > mrun) {
        float es = __expf(mrun - s);
        mrun = s;
        lrun = lrun * es + 1.0f;
        #pragma unroll
        for (int i = 0; i < 4; ++i) {
          float4 vv = vj[i];
          av[i].x = av[i].x * es + vv.x;
          av[i].y = av[i].y * es + vv.y;
          av[i].z = av[i].z * es + vv.z;
          av[i].w = av[i].w * es + vv.w;
        }
      } else {
        float pr = __expf(s - mrun);
        lrun += pr;
        #pragma unroll
        for (int i = 0; i < 4; ++i) {
          float4 vv = vj[i];
          av[i].x += pr * vv.x;
          av[i].y += pr * vv.y;
          av[i].z += pr * vv.z;
          av[i].w += pr * vv.w;
        }
      }
    }
  }
  float inv = 1.0f / lrun;
  float o[16];
  #pragma unroll
  for (int i = 0; i < 4; ++i) {
    o[4*i]   = av[i].x * inv; o[4*i+1] = av[i].y * inv;
    o[4*i+2] = av[i].z * inv; o[4*i+3] = av[i].w * inv;
  }
  unsigned short* orow = out + (size_t)row * DM + h * HD + d0;
  uint4 s0, s1;
  s0.x = packbf(o[0],  o[1]);  s0.y = packbf(o[2],  o[3]);
  s0.z = packbf(o[4],  o[5]);  s0.w = packbf(o[6],  o[7]);
  s1.x = packbf(o[8],  o[9]);  s1.y = packbf(o[10], o[11]);
  s1.z = packbf(o[12], o[13]); s1.w = packbf(o[14], o[15]);
  ((uint4*)orow)[0] = s0; ((uint4*)orow)[1] = s1;
}

// ---------------- gelu(g) * u -> bf16 ----------------
__device__ __forceinline__ float gelu_t(float x) {
  float x3 = x * x * x;
  return 0.5f * x * (1.0f + tanhf(0.7978845608028654f * (x + 0.044715f * x3)));
}
__global__ void gelu_mul_kernel(const float* __restrict__ gu,
                                unsigned short* __restrict__ m) {
  int i = blockIdx.x * blockDim.x + threadIdx.x;  // over T*FF/4
  int row = i >> 9;            // FF/4 = 512 float4 per row
  int c4 = (i & 511) * 4;
  float4 g = *(const float4*)(gu + (size_t)row * (2 * FFD) + c4);
  float4 u = *(const float4*)(gu + (size_t)row * (2 * FFD) + FFD + c4);
  float o0 = gelu_t(g.x) * u.x, o1 = gelu_t(g.y) * u.y;
  float o2 = gelu_t(g.z) * u.z, o3 = gelu_t(g.w) * u.w;
  uint2 st; st.x = packbf(o0, o1); st.y = packbf(o2, o3);
  *(uint2*)(m + (size_t)row * FFD + c4) = st;
}

extern "C" void kernel_launch(void* const* d_in, const int* in_sizes, int n_in,
                              void* d_out, int out_size, void* d_ws, size_t ws_size,
                              hipStream_t stream) {
  const int*   idx   = (const int*)d_in[0];
  const float* embed = (const float*)d_in[1];
  const float* ln1   = (const float*)d_in[2];
  const float* Wq    = (const float*)d_in[3];
  const float* Wk    = (const float*)d_in[4];
  const float* Wv    = (const float*)d_in[5];
  const float* Wo    = (const float*)d_in[6];
  const float* ln2   = (const float*)d_in[7];
  const float* Wg    = (const float*)d_in[8];
  const float* Wu    = (const float*)d_in[9];
  const float* Wd    = (const float*)d_in[10];
  const float* normf = (const float*)d_in[11];
  float* out = (float*)d_out;
  char* ws = (char*)d_ws;
  (void)in_sizes; (void)n_in; (void)out_size; (void)ws_size;

  // ---- workspace layout ----
  unsigned short* embed_bf = (unsigned short*)ws;
  size_t off = (size_t)VOC * DM * 2;                         // 49,152,000
  unsigned short* wts = (unsigned short*)(ws + off);
  const size_t LW = (size_t)QKVN * DM + (size_t)DM * DM      // qkvT + woT
                  + 2ull * FFD * DM + (size_t)DM * FFD;      // wguT + wdT
  off += LW * 2ull * NL;                                     // +50,331,648
  float* xf = (float*)(ws + off);            off += (size_t)TSEQ * DM * 4;
  unsigned short* h_bf = (unsigned short*)(ws + off);    off += (size_t)TSEQ * DM * 2;
  unsigned short* qkv_bf = (unsigned short*)(ws + off);  off += (size_t)TSEQ * QKVN * 2;
  unsigned short* attn_bf = (unsigned short*)(ws + off); off += (size_t)TSEQ * DM * 2;
  float* gu_f = (float*)(ws + off);          off += (size_t)TSEQ * 2 * FFD * 4;
  unsigned short* m_bf = (unsigned short*)(ws + off);    off += (size_t)TSEQ * FFD * 2;

  // ---- prep: embed cast + weight transpose/cast ----
  cast_bf16_kernel<<<(VOC * DM / 4 + 255) / 256, 256, 0, stream>>>(embed, embed_bf, VOC * DM / 4);

  for (int l = 0; l < NL; ++l) {
    unsigned short* base = wts + (size_t)l * LW;
    unsigned short* qkvT = base;
    unsigned short* woT  = base + (size_t)QKVN * DM;
    unsigned short* wguT = woT + (size_t)DM * DM;
    unsigned short* wdT  = wguT + 2ull * FFD * DM;
    transpose_cast_kernel<<<dim3(24, 24), dim3(32, 8), 0, stream>>>(Wq + (size_t)l * 589824, qkvT, 768, 768);
    transpose_cast_kernel<<<dim3(8, 24),  dim3(32, 8), 0, stream>>>(Wk + (size_t)l * 196608, qkvT + 768ull * 768, 768, 256);
    transpose_cast_kernel<<<dim3(8, 24),  dim3(32, 8), 0, stream>>>(Wv + (size_t)l * 196608, qkvT + 1024ull * 768, 768, 256);
    transpose_cast_kernel<<<dim3(24, 24), dim3(32, 8), 0, stream>>>(Wo + (size_t)l * 589824, woT, 768, 768);
    transpose_cast_kernel<<<dim3(64, 24), dim3(32, 8), 0, stream>>>(Wg + (size_t)l * 1572864, wguT, 768, 2048);
    transpose_cast_kernel<<<dim3(64, 24), dim3(32, 8), 0, stream>>>(Wu + (size_t)l * 1572864, wguT + 2048ull * 768, 768, 2048);
    transpose_cast_kernel<<<dim3(24, 64), dim3(32, 8), 0, stream>>>(Wd + (size_t)l * 1572864, wdT, 2048, 768);
  }

  gather_kernel<<<TSEQ, 192, 0, stream>>>(idx, embed, xf);

  for (int l = 0; l < NL; ++l) {
    unsigned short* base = wts + (size_t)l * LW;
    unsigned short* qkvT = base;
    unsigned short* woT  = base + (size_t)QKVN * DM;
    unsigned short* wguT = woT + (size_t)DM * DM;
    unsigned short* wdT  = wguT + 2ull * FFD * DM;

    rmsnorm_kernel<<<TSEQ, 256, 0, stream>>>(xf, ln1 + (size_t)l * DM, h_bf);
    gemm_bt_kernel<2><<<dim3(QKVN / 128, TSEQ / 128), 256, 0, stream>>>(h_bf, qkvT, qkv_bf, QKVN, DM);
    rope_kernel<<<TSEQ, 256, 0, stream>>>(qkv_bf);
    attn_kernel<<<dim3(TSEQ / 64, NH), 256, 0, stream>>>(qkv_bf, attn_bf);
    gemm_bt_kernel<1><<<dim3(DM / 128, TSEQ / 128), 256, 0, stream>>>(attn_bf, woT, xf, DM, DM);
    rmsnorm_kernel<<<TSEQ, 256, 0, stream>>>(xf, ln2 + (size_t)l * DM, h_bf);
    gemm_bt_kernel<0><<<dim3(2 * FFD / 128, TSEQ / 128), 256, 0, stream>>>(h_bf, wguT, gu_f, 2 * FFD, DM);
    gelu_mul_kernel<<<TSEQ * FFD / 4 / 256, 256, 0, stream>>>(gu_f, m_bf);
    gemm_bt_kernel<1><<<dim3(DM / 128, TSEQ / 128), 256, 0, stream>>>(m_bf, wdT, xf, DM, FFD);
  }

  rmsnorm_kernel<<<TSEQ, 256, 0, stream>>>(xf, normf, h_bf);
  gemm_bt_kernel<0><<<dim3(VOC / 128, TSEQ / 128), 256, 0, stream>>>(h_bf, embed_bf, out, VOC, DM);
}

// Round 2
// 1199.254 us; speedup vs baseline: 2.8756x; 2.8756x over previous
//
#include <hip/hip_runtime.h>

#define TSEQ 2048
#define DM   768
#define NH   12
#define NKV  4
#define HD   64
#define FFD  2048
#define NL   4
#define VOC  32000
#define QKVN 1280   // 768 q + 256 k + 256 v

typedef __attribute__((ext_vector_type(8))) short short8;
typedef __attribute__((ext_vector_type(4))) float f32x4;

__device__ __forceinline__ unsigned short f2b(float f) {
  unsigned int u = __float_as_uint(f);
  u += 0x7fffu + ((u >> 16) & 1u);
  return (unsigned short)(u >> 16);
}
__device__ __forceinline__ float b2f(unsigned short u) {
  return __uint_as_float(((unsigned int)u) << 16);
}
__device__ __forceinline__ unsigned int packbf(float a, float b) {
  return (unsigned int)f2b(a) | ((unsigned int)f2b(b) << 16);
}

// ---------------- cast f32 -> bf16 (vectorized x4) ----------------
__global__ void cast_bf16_kernel(const float* __restrict__ src,
                                 unsigned short* __restrict__ dst, int n4) {
  int i = blockIdx.x * blockDim.x + threadIdx.x;
  if (i >= n4) return;
  float4 v = ((const float4*)src)[i];
  uint2 o; o.x = packbf(v.x, v.y); o.y = packbf(v.z, v.w);
  ((uint2*)dst)[i] = o;
}

// ---------------- transpose + cast: src [K][N] f32 -> dst [N][K] bf16 ----------------
__global__ void transpose_cast_kernel(const float* __restrict__ src,
                                      unsigned short* __restrict__ dst,
                                      int K, int N) {
  __shared__ float tile[32][33];
  int n0 = blockIdx.x * 32, k0 = blockIdx.y * 32;
  int tx = threadIdx.x, ty = threadIdx.y;  // 32 x 8
  #pragma unroll
  for (int i = 0; i < 4; ++i) {
    int r = ty + i * 8;
    tile[r][tx] = src[(size_t)(k0 + r) * N + n0 + tx];
  }
  __syncthreads();
  #pragma unroll
  for (int i = 0; i < 4; ++i) {
    int r = ty + i * 8;
    dst[(size_t)(n0 + r) * K + k0 + tx] = f2b(tile[tx][r]);
  }
}

// ---------------- embedding gather ----------------
__global__ void gather_kernel(const int* __restrict__ idx,
                              const float* __restrict__ embed,
                              float* __restrict__ x) {
  int row = blockIdx.x; int t = threadIdx.x;  // 192 threads, float4 each
  int id = idx[row];
  ((float4*)(x + (size_t)row * DM))[t] = ((const float4*)(embed + (size_t)id * DM))[t];
}

// ---------------- RMSNorm: f32 in -> bf16 out ----------------
__global__ void rmsnorm_kernel(const float* __restrict__ x,
                               const float* __restrict__ w,
                               unsigned short* __restrict__ out) {
  int row = blockIdx.x; int t = threadIdx.x;  // 256 threads, D=768
  const float* xr = x + (size_t)row * DM;
  float v0 = xr[t], v1 = xr[t + 256], v2 = xr[t + 512];
  float s = v0*v0 + v1*v1 + v2*v2;
  #pragma unroll
  for (int off = 1; off < 64; off <<= 1) s += __shfl_xor(s, off);
  __shared__ float red[4];
  if ((t & 63) == 0) red[t >> 6] = s;
  __syncthreads();
  float tot = red[0] + red[1] + red[2] + red[3];
  float rs = rsqrtf(tot * (1.0f / DM) + 1e-6f);
  unsigned short* orow = out + (size_t)row * DM;
  orow[t]       = f2b(w[t]       * v0 * rs);
  orow[t + 256] = f2b(w[t + 256] * v1 * rs);
  orow[t + 512] = f2b(w[t + 512] * v2 * rs);
}

// ---------------- RoPE in-place on q (cols 0..767, 12 heads) and k (768..1023, 4 heads) ----------------
__global__ void rope_kernel(unsigned short* __restrict__ qkv) {
  int pos = blockIdx.x; int t = threadIdx.x;
  int head = t >> 4;        // 0..15 (12 q heads + 4 k heads)
  int pi = t & 15;
  int base = (head < NH) ? head * HD : DM + (head - NH) * HD;
  unsigned short* row = qkv + (size_t)pos * QKVN + base;
  #pragma unroll
  for (int pp = 0; pp < 2; ++pp) {
    int i = pi * 2 + pp;  // 0..31
    float inv = exp2f(-(float)i * (13.287712379549449f / 32.0f));
    float ang = (float)pos * inv;
    float sv, cv; sincosf(ang, &sv, &cv);
    float x1 = b2f(row[i]), x2 = b2f(row[i + 32]);
    row[i]      = f2b(x1 * cv - x2 * sv);
    row[i + 32] = f2b(x2 * cv + x1 * sv);
  }
}

// ---------------- GEMM: C[M][N] = A[M][K] @ Bt[N][K]^T ----------------
// OUT: 0 = f32 store, 1 = f32 +=, 2 = bf16 store
template <int OUT>
__global__ __launch_bounds__(256) void gemm_bt_kernel(
    const unsigned short* __restrict__ A, const unsigned short* __restrict__ Bt,
    void* __restrict__ Cv, int N, int K) {
  __shared__ unsigned short As[128 * 40];
  __shared__ unsigned short Bs[128 * 40];
  int tid = threadIdx.x;
  int m0 = blockIdx.y * 128, n0 = blockIdx.x * 128;
  int lane = tid & 63, wave = tid >> 6;
  int wr = (wave >> 1) * 64, wc = (wave & 1) * 64;
  int l16 = lane & 15, lk8 = (lane >> 4) * 8;
  f32x4 acc[4][4];
  #pragma unroll
  for (int m = 0; m < 4; ++m)
    #pragma unroll
    for (int n = 0; n < 4; ++n) acc[m][n] = (f32x4){0.f, 0.f, 0.f, 0.f};
  const unsigned short* Abase = A + (size_t)m0 * K;
  const unsigned short* Bbase = Bt + (size_t)n0 * K;
  int r0 = tid >> 2;            // 0..63
  int c0 = (tid & 3) * 8;       // 0,8,16,24
  for (int k0 = 0; k0 < K; k0 += 32) {
    uint4 a0 = *(const uint4*)(Abase + (size_t)r0 * K + k0 + c0);
    uint4 a1 = *(const uint4*)(Abase + (size_t)(r0 + 64) * K + k0 + c0);
    uint4 b0 = *(const uint4*)(Bbase + (size_t)r0 * K + k0 + c0);
    uint4 b1 = *(const uint4*)(Bbase + (size_t)(r0 + 64) * K + k0 + c0);
    *(uint4*)&As[r0 * 40 + c0] = a0;
    *(uint4*)&As[(r0 + 64) * 40 + c0] = a1;
    *(uint4*)&Bs[r0 * 40 + c0] = b0;
    *(uint4*)&Bs[(r0 + 64) * 40 + c0] = b1;
    __syncthreads();
    short8 af[4], bfr[4];
    #pragma unroll
    for (int m = 0; m < 4; ++m) af[m]  = *(const short8*)&As[(wr + m*16 + l16) * 40 + lk8];
    #pragma unroll
    for (int n = 0; n < 4; ++n) bfr[n] = *(const short8*)&Bs[(wc + n*16 + l16) * 40 + lk8];
    #pragma unroll
    for (int m = 0; m < 4; ++m)
      #pragma unroll
      for (int n = 0; n < 4; ++n)
        acc[m][n] = __builtin_amdgcn_mfma_f32_16x16x32_bf16(af[m], bfr[n], acc[m][n], 0, 0, 0);
    __syncthreads();
  }
  // C/D layout: col = lane&15, row = (lane>>4)*4 + reg   [learn_hip m89/m91]
  if (OUT == 2) {
    unsigned short* C = (unsigned short*)Cv;
    #pragma unroll
    for (int m = 0; m < 4; ++m)
      #pragma unroll
      for (int r = 0; r < 4; ++r) {
        size_t row = (size_t)(m0 + wr + m*16 + ((lane >> 4) << 2) + r);
        unsigned short* Cr = C + row * N + n0 + wc + l16;
        #pragma unroll
        for (int n = 0; n < 4; ++n) Cr[n * 16] = f2b(acc[m][n][r]);
      }
  } else {
    float* C = (float*)Cv;
    #pragma unroll
    for (int m = 0; m < 4; ++m)
      #pragma unroll
      for (int r = 0; r < 4; ++r) {
        size_t row = (size_t)(m0 + wr + m*16 + ((lane >> 4) << 2) + r);
        float* Cr = C + row * N + n0 + wc + l16;
        #pragma unroll
        for (int n = 0; n < 4; ++n) {
          if (OUT == 1) Cr[n * 16] += acc[m][n][r];
          else          Cr[n * 16]  = acc[m][n][r];
        }
      }
  }
}

// ---------------- MFMA flash attention, causal, GQA ----------------
// grid (TSEQ/64, NH), 256 threads. Wave w owns q rows [r0+16w, r0+16w+16).
// LDS: K row-major [key][64], V transposed [d][key], per-wave P [q][64];
// all XOR-swizzled: 16B-chunk c of row r stored at chunk (c ^ (r&7)).
__global__ __launch_bounds__(256) void attn_mfma_kernel(
    const unsigned short* __restrict__ qkv, unsigned short* __restrict__ out) {
  __shared__ unsigned short Ks[64 * 64];
  __shared__ unsigned short Vt[64 * 64];
  __shared__ unsigned short Ps[4][16 * 64];
  int h = blockIdx.y;
  int qt = blockIdx.x;
  int r0 = qt * 64;
  int kvh = h / 3;           // N_REP = 3
  int t = threadIdx.x;
  int lane = t & 63, w = t >> 6;
  int l16 = lane & 15, g = lane >> 4;

  // Q fragments: A-layout row=lane&15, k = 8*(lane>>4)+j (+32 per chunk)
  int qr = r0 + w * 16 + l16;
  const unsigned short* qrow = qkv + (size_t)qr * QKVN + h * HD;
  short8 aq0 = *(const short8*)(qrow + 8 * g);
  short8 aq1 = *(const short8*)(qrow + 32 + 8 * g);

  f32x4 o_acc[4];
  float mrun[4], lrun[4];
  #pragma unroll
  for (int i = 0; i < 4; ++i) { o_acc[i] = (f32x4){0.f,0.f,0.f,0.f}; mrun[i] = -1e30f; lrun[i] = 0.f; }

  int nt = qt + 1;
  for (int kt = 0; kt < nt; ++kt) {
    int kb = kt * 64;
    if (kt) __syncthreads();
    {
      // staging: wave w handles dim chunk [16w,16w+16) for all 64 keys (key = lane)
      const unsigned short* krow = qkv + (size_t)(kb + lane) * QKVN + DM + kvh * HD + 16 * w;
      uint4 k0 = ((const uint4*)krow)[0];
      uint4 k1 = ((const uint4*)krow)[1];
      uint4 v0 = ((const uint4*)(krow + NKV * HD))[0];
      uint4 v1 = ((const uint4*)(krow + NKV * HD))[1];
      int k7 = lane & 7;
      *(uint4*)&Ks[lane * 64 + (((2*w)     ^ k7) << 3)] = k0;
      *(uint4*)&Ks[lane * 64 + (((2*w + 1) ^ k7) << 3)] = k1;
      unsigned short tv[16];
      *(uint4*)&tv[0] = v0; *(uint4*)&tv[8] = v1;
      #pragma unroll
      for (int j = 0; j < 16; ++j) {
        int d = 16 * w + j;
        Vt[d * 64 + ((((lane >> 3) ^ (d & 7)) << 3) + (lane & 7))] = tv[j];
      }
    }
    __syncthreads();

    // S = Q K^T  (C-layout: key = lane&15 + 16nb, q = g*4 + r)
    f32x4 s_acc[4];
    #pragma unroll
    for (int nb = 0; nb < 4; ++nb) s_acc[nb] = (f32x4){0.f,0.f,0.f,0.f};
    #pragma unroll
    for (int nb = 0; nb < 4; ++nb) {
      int key = nb * 16 + l16;
      short8 bk0 = *(const short8*)&Ks[key * 64 + ((g       ^ (key & 7)) << 3)];
      short8 bk1 = *(const short8*)&Ks[key * 64 + (((4 + g) ^ (key & 7)) << 3)];
      s_acc[nb] = __builtin_amdgcn_mfma_f32_16x16x32_bf16(aq0, bk0, s_acc[nb], 0, 0, 0);
      s_acc[nb] = __builtin_amdgcn_mfma_f32_16x16x32_bf16(aq1, bk1, s_acc[nb], 0, 0, 0);
    }

    bool diag = (kt == qt);
    #pragma unroll
    for (int r = 0; r < 4; ++r) {
      int qg = r0 + w * 16 + g * 4 + r;
      float sv[4];
      #pragma unroll
      for (int nb = 0; nb < 4; ++nb) {
        sv[nb] = s_acc[nb][r] * 0.125f;
        if (diag && (kb + nb * 16 + l16 > qg)) sv[nb] = -1e30f;
      }
      float mx = fmaxf(fmaxf(sv[0], sv[1]), fmaxf(sv[2], sv[3]));
      mx = fmaxf(mx, __shfl_xor(mx, 1));
      mx = fmaxf(mx, __shfl_xor(mx, 2));
      mx = fmaxf(mx, __shfl_xor(mx, 4));
      mx = fmaxf(mx, __shfl_xor(mx, 8));
      float mnew = fmaxf(mrun[r], mx);
      float es = __expf(mrun[r] - mnew);
      float rs = 0.f;
      #pragma unroll
      for (int nb = 0; nb < 4; ++nb) { sv[nb] = __expf(sv[nb] - mnew); rs += sv[nb]; }
      rs += __shfl_xor(rs, 1);
      rs += __shfl_xor(rs, 2);
      rs += __shfl_xor(rs, 4);
      rs += __shfl_xor(rs, 8);
      lrun[r] = lrun[r] * es + rs;
      mrun[r] = mnew;
      #pragma unroll
      for (int db = 0; db < 4; ++db) o_acc[db][r] *= es;
      int qloc = g * 4 + r, q7 = qloc & 7;
      #pragma unroll
      for (int nb = 0; nb < 4; ++nb) {
        int key = nb * 16 + l16;
        Ps[w][qloc * 64 + ((((key >> 3) ^ q7) << 3) + (key & 7))] = f2b(sv[nb]);
      }
    }

    // O += P V   (A = P: row=q=lane&15, k=key; B = Vt: n=d=lane&15, k=key)
    #pragma unroll
    for (int kc = 0; kc < 2; ++kc) {
      short8 pa = *(const short8*)&Ps[w][l16 * 64 + (((4 * kc + g) ^ (l16 & 7)) << 3)];
      #pragma unroll
      for (int db = 0; db < 4; ++db) {
        int d = db * 16 + l16;
        short8 bv = *(const short8*)&Vt[d * 64 + (((4 * kc + g) ^ (d & 7)) << 3)];
        o_acc[db] = __builtin_amdgcn_mfma_f32_16x16x32_bf16(pa, bv, o_acc[db], 0, 0, 0);
      }
    }
  }

  // epilogue: normalize and store (O layout: d = lane&15 + 16db, q = g*4 + r)
  #pragma unroll
  for (int r = 0; r < 4; ++r) {
    int qg = r0 + w * 16 + g * 4 + r;
    float inv = 1.0f / lrun[r];
    unsigned short* orow = out + (size_t)qg * DM + h * HD + l16;
    #pragma unroll
    for (int db = 0; db < 4; ++db) orow[db * 16] = f2b(o_acc[db][r] * inv);
  }
}

// ---------------- gelu(g) * u -> bf16 ----------------
__device__ __forceinline__ float gelu_t(float x) {
  float x3 = x * x * x;
  return 0.5f * x * (1.0f + tanhf(0.7978845608028654f * (x + 0.044715f * x3)));
}
__global__ void gelu_mul_kernel(const float* __restrict__ gu,
                                unsigned short* __restrict__ m) {
  int i = blockIdx.x * blockDim.x + threadIdx.x;  // over T*FF/4
  int row = i >> 9;            // FF/4 = 512 float4 per row
  int c4 = (i & 511) * 4;
  float4 g = *(const float4*)(gu + (size_t)row * (2 * FFD) + c4);
  float4 u = *(const float4*)(gu + (size_t)row * (2 * FFD) + FFD + c4);
  float o0 = gelu_t(g.x) * u.x, o1 = gelu_t(g.y) * u.y;
  float o2 = gelu_t(g.z) * u.z, o3 = gelu_t(g.w) * u.w;
  uint2 st; st.x = packbf(o0, o1); st.y = packbf(o2, o3);
  *(uint2*)(m + (size_t)row * FFD + c4) = st;
}

extern "C" void kernel_launch(void* const* d_in, const int* in_sizes, int n_in,
                              void* d_out, int out_size, void* d_ws, size_t ws_size,
                              hipStream_t stream) {
  const int*   idx   = (const int*)d_in[0];
  const float* embed = (const float*)d_in[1];
  const float* ln1   = (const float*)d_in[2];
  const float* Wq    = (const float*)d_in[3];
  const float* Wk    = (const float*)d_in[4];
  const float* Wv    = (const float*)d_in[5];
  const float* Wo    = (const float*)d_in[6];
  const float* ln2   = (const float*)d_in[7];
  const float* Wg    = (const float*)d_in[8];
  const float* Wu    = (const float*)d_in[9];
  const float* Wd    = (const float*)d_in[10];
  const float* normf = (const float*)d_in[11];
  float* out = (float*)d_out;
  char* ws = (char*)d_ws;
  (void)in_sizes; (void)n_in; (void)out_size; (void)ws_size;

  // ---- workspace layout ----
  unsigned short* embed_bf = (unsigned short*)ws;
  size_t off = (size_t)VOC * DM * 2;
  unsigned short* wts = (unsigned short*)(ws + off);
  const size_t LW = (size_t)QKVN * DM + (size_t)DM * DM
                  + 2ull * FFD * DM + (size_t)DM * FFD;
  off += LW * 2ull * NL;
  float* xf = (float*)(ws + off);            off += (size_t)TSEQ * DM * 4;
  unsigned short* h_bf = (unsigned short*)(ws + off);    off += (size_t)TSEQ * DM * 2;
  unsigned short* qkv_bf = (unsigned short*)(ws + off);  off += (size_t)TSEQ * QKVN * 2;
  unsigned short* attn_bf = (unsigned short*)(ws + off); off += (size_t)TSEQ * DM * 2;
  float* gu_f = (float*)(ws + off);          off += (size_t)TSEQ * 2 * FFD * 4;
  unsigned short* m_bf = (unsigned short*)(ws + off);    off += (size_t)TSEQ * FFD * 2;

  // ---- prep: embed cast + weight transpose/cast ----
  cast_bf16_kernel<<<(VOC * DM / 4 + 255) / 256, 256, 0, stream>>>(embed, embed_bf, VOC * DM / 4);

  for (int l = 0; l < NL; ++l) {
    unsigned short* base = wts + (size_t)l * LW;
    unsigned short* qkvT = base;
    unsigned short* woT  = base + (size_t)QKVN * DM;
    unsigned short* wguT = woT + (size_t)DM * DM;
    unsigned short* wdT  = wguT + 2ull * FFD * DM;
    transpose_cast_kernel<<<dim3(24, 24), dim3(32, 8), 0, stream>>>(Wq + (size_t)l * 589824, qkvT, 768, 768);
    transpose_cast_kernel<<<dim3(8, 24),  dim3(32, 8), 0, stream>>>(Wk + (size_t)l * 196608, qkvT + 768ull * 768, 768, 256);
    transpose_cast_kernel<<<dim3(8, 24),  dim3(32, 8), 0, stream>>>(Wv + (size_t)l * 196608, qkvT + 1024ull * 768, 768, 256);
    transpose_cast_kernel<<<dim3(24, 24), dim3(32, 8), 0, stream>>>(Wo + (size_t)l * 589824, woT, 768, 768);
    transpose_cast_kernel<<<dim3(64, 24), dim3(32, 8), 0, stream>>>(Wg + (size_t)l * 1572864, wguT, 768, 2048);
    transpose_cast_kernel<<<dim3(64, 24), dim3(32, 8), 0, stream>>>(Wu + (size_t)l * 1572864, wguT + 2048ull * 768, 768, 2048);
    transpose_cast_kernel<<<dim3(24, 64), dim3(32, 8), 0, stream>>>(Wd + (size_t)l * 1572864, wdT, 2048, 768);
  }

  gather_kernel<<<TSEQ, 192, 0, stream>>>(idx, embed, xf);

  for (int l = 0; l < NL; ++l) {
    unsigned short* base = wts + (size_t)l * LW;
    unsigned short* qkvT = base;
    unsigned short* woT  = base + (size_t)QKVN * DM;
    unsigned short* wguT = woT + (size_t)DM * DM;
    unsigned short* wdT  = wguT + 2ull * FFD * DM;

    rmsnorm_kernel<<<TSEQ, 256, 0, stream>>>(xf, ln1 + (size_t)l * DM, h_bf);
    gemm_bt_kernel<2><<<dim3(QKVN / 128, TSEQ / 128), 256, 0, stream>>>(h_bf, qkvT, qkv_bf, QKVN, DM);
    rope_kernel<<<TSEQ, 256, 0, stream>>>(qkv_bf);
    attn_mfma_kernel<<<dim3(TSEQ / 64, NH), 256, 0, stream>>>(qkv_bf, attn_bf);
    gemm_bt_kernel<1><<<dim3(DM / 128, TSEQ / 128), 256, 0, stream>>>(attn_bf, woT, xf, DM, DM);
    rmsnorm_kernel<<<TSEQ, 256, 0, stream>>>(xf, ln2 + (size_t)l * DM, h_bf);
    gemm_bt_kernel<0><<<dim3(2 * FFD / 128, TSEQ / 128), 256, 0, stream>>>(h_bf, wguT, gu_f, 2 * FFD, DM);
    gelu_mul_kernel<<<TSEQ * FFD / 4 / 256, 256, 0, stream>>>(gu_f, m_bf);
    gemm_bt_kernel<1><<<dim3(DM / 128, TSEQ / 128), 256, 0, stream>>>(m_bf, wdT, xf, DM, FFD);
  }

  rmsnorm_kernel<<<TSEQ, 256, 0, stream>>>(xf, normf, h_bf);
  gemm_bt_kernel<0><<<dim3(VOC / 128, TSEQ / 128), 256, 0, stream>>>(h_bf, embed_bf, out, VOC, DM);
}

// Round 3
// 1192.116 us; speedup vs baseline: 2.8928x; 1.0060x over previous
//
#include <hip/hip_runtime.h>

#define TSEQ 2048
#define DM   768
#define NH   12
#define NKV  4
#define HD   64
#define FFD  2048
#define NL   4
#define VOC  32000
#define QKVN 1280   // 768 q + 256 k + 256 v

typedef __attribute__((ext_vector_type(8))) short short8;
typedef __attribute__((ext_vector_type(4))) float f32x4;

__device__ __forceinline__ unsigned short f2b(float f) {
  unsigned int u = __float_as_uint(f);
  u += 0x7fffu + ((u >> 16) & 1u);
  return (unsigned short)(u >> 16);
}
__device__ __forceinline__ float b2f(unsigned short u) {
  return __uint_as_float(((unsigned int)u) << 16);
}
__device__ __forceinline__ unsigned int packbf(float a, float b) {
  return (unsigned int)f2b(a) | ((unsigned int)f2b(b) << 16);
}

// ---------------- cast f32 -> bf16 (vectorized x4) ----------------
__global__ void cast_bf16_kernel(const float* __restrict__ src,
                                 unsigned short* __restrict__ dst, int n4) {
  int i = blockIdx.x * blockDim.x + threadIdx.x;
  if (i >= n4) return;
  float4 v = ((const float4*)src)[i];
  uint2 o; o.x = packbf(v.x, v.y); o.y = packbf(v.z, v.w);
  ((uint2*)dst)[i] = o;
}

// ---------------- transpose + cast: src [K][N] f32 -> dst [N][K] bf16 ----------------
__global__ void transpose_cast_kernel(const float* __restrict__ src,
                                      unsigned short* __restrict__ dst,
                                      int K, int N) {
  __shared__ float tile[32][33];
  int n0 = blockIdx.x * 32, k0 = blockIdx.y * 32;
  int tx = threadIdx.x, ty = threadIdx.y;  // 32 x 8
  #pragma unroll
  for (int i = 0; i < 4; ++i) {
    int r = ty + i * 8;
    tile[r][tx] = src[(size_t)(k0 + r) * N + n0 + tx];
  }
  __syncthreads();
  #pragma unroll
  for (int i = 0; i < 4; ++i) {
    int r = ty + i * 8;
    dst[(size_t)(n0 + r) * K + k0 + tx] = f2b(tile[tx][r]);
  }
}

// ---------------- embedding gather ----------------
__global__ void gather_kernel(const int* __restrict__ idx,
                              const float* __restrict__ embed,
                              float* __restrict__ x) {
  int row = blockIdx.x; int t = threadIdx.x;  // 192 threads, float4 each
  int id = idx[row];
  ((float4*)(x + (size_t)row * DM))[t] = ((const float4*)(embed + (size_t)id * DM))[t];
}

// ---------------- RMSNorm: f32 in -> bf16 out ----------------
__global__ void rmsnorm_kernel(const float* __restrict__ x,
                               const float* __restrict__ w,
                               unsigned short* __restrict__ out) {
  int row = blockIdx.x; int t = threadIdx.x;  // 256 threads, D=768
  const float* xr = x + (size_t)row * DM;
  float v0 = xr[t], v1 = xr[t + 256], v2 = xr[t + 512];
  float s = v0*v0 + v1*v1 + v2*v2;
  #pragma unroll
  for (int off = 1; off < 64; off <<= 1) s += __shfl_xor(s, off);
  __shared__ float red[4];
  if ((t & 63) == 0) red[t >> 6] = s;
  __syncthreads();
  float tot = red[0] + red[1] + red[2] + red[3];
  float rs = rsqrtf(tot * (1.0f / DM) + 1e-6f);
  unsigned short* orow = out + (size_t)row * DM;
  orow[t]       = f2b(w[t]       * v0 * rs);
  orow[t + 256] = f2b(w[t + 256] * v1 * rs);
  orow[t + 512] = f2b(w[t + 512] * v2 * rs);
}

// ---------------- RoPE in-place on q (cols 0..767) and k (768..1023) ----------------
__global__ void rope_kernel(unsigned short* __restrict__ qkv) {
  int pos = blockIdx.x; int t = threadIdx.x;
  int head = t >> 4;        // 0..15 (12 q heads + 4 k heads)
  int pi = t & 15;
  int base = (head < NH) ? head * HD : DM + (head - NH) * HD;
  unsigned short* row = qkv + (size_t)pos * QKVN + base;
  #pragma unroll
  for (int pp = 0; pp < 2; ++pp) {
    int i = pi * 2 + pp;  // 0..31
    float inv = exp2f(-(float)i * (13.287712379549449f / 32.0f));
    float ang = (float)pos * inv;
    float sv, cv; sincosf(ang, &sv, &cv);
    float x1 = b2f(row[i]), x2 = b2f(row[i + 32]);
    row[i]      = f2b(x1 * cv - x2 * sv);
    row[i + 32] = f2b(x2 * cv + x1 * sv);
  }
}

// ---------------- GEMM: C[M][N] = A[M][K] @ Bt[N][K]^T ----------------
// 1D grid = ntiles*16 blocks (M fixed 2048 -> 16 m-tiles). XCD-chunked
// bijective swizzle (m204): each XCD owns a contiguous n-panel range, m inner.
// OUT: 0 = f32 store, 1 = f32 +=, 2 = bf16 store
template <int OUT>
__global__ __launch_bounds__(256) void gemm_bt_kernel(
    const unsigned short* __restrict__ A, const unsigned short* __restrict__ Bt,
    void* __restrict__ Cv, int N, int K) {
  __shared__ unsigned short As[128 * 40];
  __shared__ unsigned short Bs[128 * 40];
  int bid = blockIdx.x, nwg = gridDim.x;
  int wgid = (bid & 7) * (nwg >> 3) + (bid >> 3);
  int m0 = (wgid & 15) * 128;
  int n0 = (wgid >> 4) * 128;
  int tid = threadIdx.x;
  int lane = tid & 63, wave = tid >> 6;
  int wr = (wave >> 1) * 64, wc = (wave & 1) * 64;
  int l16 = lane & 15, lk8 = (lane >> 4) * 8;
  f32x4 acc[4][4];
  #pragma unroll
  for (int m = 0; m < 4; ++m)
    #pragma unroll
    for (int n = 0; n < 4; ++n) acc[m][n] = (f32x4){0.f, 0.f, 0.f, 0.f};
  const unsigned short* Abase = A + (size_t)m0 * K;
  const unsigned short* Bbase = Bt + (size_t)n0 * K;
  int r0 = tid >> 2;            // 0..63
  int c0 = (tid & 3) * 8;       // 0,8,16,24
  for (int k0 = 0; k0 < K; k0 += 32) {
    uint4 a0 = *(const uint4*)(Abase + (size_t)r0 * K + k0 + c0);
    uint4 a1 = *(const uint4*)(Abase + (size_t)(r0 + 64) * K + k0 + c0);
    uint4 b0 = *(const uint4*)(Bbase + (size_t)r0 * K + k0 + c0);
    uint4 b1 = *(const uint4*)(Bbase + (size_t)(r0 + 64) * K + k0 + c0);
    *(uint4*)&As[r0 * 40 + c0] = a0;
    *(uint4*)&As[(r0 + 64) * 40 + c0] = a1;
    *(uint4*)&Bs[r0 * 40 + c0] = b0;
    *(uint4*)&Bs[(r0 + 64) * 40 + c0] = b1;
    __syncthreads();
    short8 af[4], bfr[4];
    #pragma unroll
    for (int m = 0; m < 4; ++m) af[m]  = *(const short8*)&As[(wr + m*16 + l16) * 40 + lk8];
    #pragma unroll
    for (int n = 0; n < 4; ++n) bfr[n] = *(const short8*)&Bs[(wc + n*16 + l16) * 40 + lk8];
    #pragma unroll
    for (int m = 0; m < 4; ++m)
      #pragma unroll
      for (int n = 0; n < 4; ++n)
        acc[m][n] = __builtin_amdgcn_mfma_f32_16x16x32_bf16(af[m], bfr[n], acc[m][n], 0, 0, 0);
    __syncthreads();
  }
  // C/D layout: col = lane&15, row = (lane>>4)*4 + reg   [learn_hip m89/m91]
  if (OUT == 2) {
    unsigned short* C = (unsigned short*)Cv;
    #pragma unroll
    for (int m = 0; m < 4; ++m)
      #pragma unroll
      for (int r = 0; r < 4; ++r) {
        size_t row = (size_t)(m0 + wr + m*16 + ((lane >> 4) << 2) + r);
        unsigned short* Cr = C + row * N + n0 + wc + l16;
        #pragma unroll
        for (int n = 0; n < 4; ++n) Cr[n * 16] = f2b(acc[m][n][r]);
      }
  } else {
    float* C = (float*)Cv;
    #pragma unroll
    for (int m = 0; m < 4; ++m)
      #pragma unroll
      for (int r = 0; r < 4; ++r) {
        size_t row = (size_t)(m0 + wr + m*16 + ((lane >> 4) << 2) + r);
        float* Cr = C + row * N + n0 + wc + l16;
        #pragma unroll
        for (int n = 0; n < 4; ++n) {
          if (OUT == 1) Cr[n * 16] += acc[m][n][r];
          else          Cr[n * 16]  = acc[m][n][r];
        }
      }
  }
}

// ---------------- gelu ----------------
__device__ __forceinline__ float gelu_t(float x) {
  float x3 = x * x * x;
  return 0.5f * x * (1.0f + tanhf(0.7978845608028654f * (x + 0.044715f * x3)));
}

// ---------------- fused gate/up GEMM + gelu-mul: m = gelu(h@Wg) * (h@Wu) ----------------
// Block computes BOTH the g-tile and matching u-tile; writes bf16 m directly.
__global__ __launch_bounds__(256) void gemm_gu_kernel(
    const unsigned short* __restrict__ A, const unsigned short* __restrict__ BtG,
    const unsigned short* __restrict__ BtU, unsigned short* __restrict__ Cm) {
  __shared__ unsigned short As[128 * 40];
  __shared__ unsigned short Bg[128 * 40];
  __shared__ unsigned short Bu[128 * 40];
  const int K = DM;
  int bid = blockIdx.x, nwg = gridDim.x;        // 256 blocks
  int wgid = (bid & 7) * (nwg >> 3) + (bid >> 3);
  int m0 = (wgid & 15) * 128;
  int n0 = (wgid >> 4) * 128;                   // over FF (2048)
  int tid = threadIdx.x;
  int lane = tid & 63, wave = tid >> 6;
  int wr = (wave >> 1) * 64, wc = (wave & 1) * 64;
  int l16 = lane & 15, lk8 = (lane >> 4) * 8;
  f32x4 accg[4][4], accu[4][4];
  #pragma unroll
  for (int m = 0; m < 4; ++m)
    #pragma unroll
    for (int n = 0; n < 4; ++n) {
      accg[m][n] = (f32x4){0.f, 0.f, 0.f, 0.f};
      accu[m][n] = (f32x4){0.f, 0.f, 0.f, 0.f};
    }
  const unsigned short* Abase = A + (size_t)m0 * K;
  const unsigned short* Gbase = BtG + (size_t)n0 * K;
  const unsigned short* Ubase = BtU + (size_t)n0 * K;
  int r0 = tid >> 2;
  int c0 = (tid & 3) * 8;
  for (int k0 = 0; k0 < K; k0 += 32) {
    uint4 a0 = *(const uint4*)(Abase + (size_t)r0 * K + k0 + c0);
    uint4 a1 = *(const uint4*)(Abase + (size_t)(r0 + 64) * K + k0 + c0);
    uint4 g0 = *(const uint4*)(Gbase + (size_t)r0 * K + k0 + c0);
    uint4 g1 = *(const uint4*)(Gbase + (size_t)(r0 + 64) * K + k0 + c0);
    uint4 u0 = *(const uint4*)(Ubase + (size_t)r0 * K + k0 + c0);
    uint4 u1 = *(const uint4*)(Ubase + (size_t)(r0 + 64) * K + k0 + c0);
    *(uint4*)&As[r0 * 40 + c0] = a0;
    *(uint4*)&As[(r0 + 64) * 40 + c0] = a1;
    *(uint4*)&Bg[r0 * 40 + c0] = g0;
    *(uint4*)&Bg[(r0 + 64) * 40 + c0] = g1;
    *(uint4*)&Bu[r0 * 40 + c0] = u0;
    *(uint4*)&Bu[(r0 + 64) * 40 + c0] = u1;
    __syncthreads();
    short8 af[4], bg[4], bu[4];
    #pragma unroll
    for (int m = 0; m < 4; ++m) af[m] = *(const short8*)&As[(wr + m*16 + l16) * 40 + lk8];
    #pragma unroll
    for (int n = 0; n < 4; ++n) {
      bg[n] = *(const short8*)&Bg[(wc + n*16 + l16) * 40 + lk8];
      bu[n] = *(const short8*)&Bu[(wc + n*16 + l16) * 40 + lk8];
    }
    #pragma unroll
    for (int m = 0; m < 4; ++m)
      #pragma unroll
      for (int n = 0; n < 4; ++n) {
        accg[m][n] = __builtin_amdgcn_mfma_f32_16x16x32_bf16(af[m], bg[n], accg[m][n], 0, 0, 0);
        accu[m][n] = __builtin_amdgcn_mfma_f32_16x16x32_bf16(af[m], bu[n], accu[m][n], 0, 0, 0);
      }
    __syncthreads();
  }
  #pragma unroll
  for (int m = 0; m < 4; ++m)
    #pragma unroll
    for (int r = 0; r < 4; ++r) {
      size_t row = (size_t)(m0 + wr + m*16 + ((lane >> 4) << 2) + r);
      unsigned short* Cr = Cm + row * FFD + n0 + wc + l16;
      #pragma unroll
      for (int n = 0; n < 4; ++n)
        Cr[n * 16] = f2b(gelu_t(accg[m][n][r]) * accu[m][n][r]);
    }
}

// ---------------- MFMA flash attention, causal, GQA ----------------
__global__ __launch_bounds__(256) void attn_mfma_kernel(
    const unsigned short* __restrict__ qkv, unsigned short* __restrict__ out) {
  __shared__ unsigned short Ks[64 * 64];
  __shared__ unsigned short Vt[64 * 64];
  __shared__ unsigned short Ps[4][16 * 64];
  int h = blockIdx.y;
  int qt = gridDim.x - 1 - blockIdx.x;   // heavy (deep-causal) blocks dispatch first
  int r0 = qt * 64;
  int kvh = h / 3;           // N_REP = 3
  int t = threadIdx.x;
  int lane = t & 63, w = t >> 6;
  int l16 = lane & 15, g = lane >> 4;

  int qr = r0 + w * 16 + l16;
  const unsigned short* qrow = qkv + (size_t)qr * QKVN + h * HD;
  short8 aq0 = *(const short8*)(qrow + 8 * g);
  short8 aq1 = *(const short8*)(qrow + 32 + 8 * g);

  f32x4 o_acc[4];
  float mrun[4], lrun[4];
  #pragma unroll
  for (int i = 0; i < 4; ++i) { o_acc[i] = (f32x4){0.f,0.f,0.f,0.f}; mrun[i] = -1e30f; lrun[i] = 0.f; }

  int nt = qt + 1;
  for (int kt = 0; kt < nt; ++kt) {
    int kb = kt * 64;
    if (kt) __syncthreads();
    {
      const unsigned short* krow = qkv + (size_t)(kb + lane) * QKVN + DM + kvh * HD + 16 * w;
      uint4 k0 = ((const uint4*)krow)[0];
      uint4 k1 = ((const uint4*)krow)[1];
      uint4 v0 = ((const uint4*)(krow + NKV * HD))[0];
      uint4 v1 = ((const uint4*)(krow + NKV * HD))[1];
      int k7 = lane & 7;
      *(uint4*)&Ks[lane * 64 + (((2*w)     ^ k7) << 3)] = k0;
      *(uint4*)&Ks[lane * 64 + (((2*w + 1) ^ k7) << 3)] = k1;
      unsigned short tv[16];
      *(uint4*)&tv[0] = v0; *(uint4*)&tv[8] = v1;
      #pragma unroll
      for (int j = 0; j < 16; ++j) {
        int d = 16 * w + j;
        Vt[d * 64 + ((((lane >> 3) ^ (d & 7)) << 3) + (lane & 7))] = tv[j];
      }
    }
    __syncthreads();

    f32x4 s_acc[4];
    #pragma unroll
    for (int nb = 0; nb < 4; ++nb) s_acc[nb] = (f32x4){0.f,0.f,0.f,0.f};
    #pragma unroll
    for (int nb = 0; nb < 4; ++nb) {
      int key = nb * 16 + l16;
      short8 bk0 = *(const short8*)&Ks[key * 64 + ((g       ^ (key & 7)) << 3)];
      short8 bk1 = *(const short8*)&Ks[key * 64 + (((4 + g) ^ (key & 7)) << 3)];
      s_acc[nb] = __builtin_amdgcn_mfma_f32_16x16x32_bf16(aq0, bk0, s_acc[nb], 0, 0, 0);
      s_acc[nb] = __builtin_amdgcn_mfma_f32_16x16x32_bf16(aq1, bk1, s_acc[nb], 0, 0, 0);
    }

    bool diag = (kt == qt);
    #pragma unroll
    for (int r = 0; r < 4; ++r) {
      int qg = r0 + w * 16 + g * 4 + r;
      float sv[4];
      #pragma unroll
      for (int nb = 0; nb < 4; ++nb) {
        sv[nb] = s_acc[nb][r] * 0.125f;
        if (diag && (kb + nb * 16 + l16 > qg)) sv[nb] = -1e30f;
      }
      float mx = fmaxf(fmaxf(sv[0], sv[1]), fmaxf(sv[2], sv[3]));
      mx = fmaxf(mx, __shfl_xor(mx, 1));
      mx = fmaxf(mx, __shfl_xor(mx, 2));
      mx = fmaxf(mx, __shfl_xor(mx, 4));
      mx = fmaxf(mx, __shfl_xor(mx, 8));
      float mnew = fmaxf(mrun[r], mx);
      float es = __expf(mrun[r] - mnew);
      float rs = 0.f;
      #pragma unroll
      for (int nb = 0; nb < 4; ++nb) { sv[nb] = __expf(sv[nb] - mnew); rs += sv[nb]; }
      rs += __shfl_xor(rs, 1);
      rs += __shfl_xor(rs, 2);
      rs += __shfl_xor(rs, 4);
      rs += __shfl_xor(rs, 8);
      lrun[r] = lrun[r] * es + rs;
      mrun[r] = mnew;
      #pragma unroll
      for (int db = 0; db < 4; ++db) o_acc[db][r] *= es;
      int qloc = g * 4 + r, q7 = qloc & 7;
      #pragma unroll
      for (int nb = 0; nb < 4; ++nb) {
        int key = nb * 16 + l16;
        Ps[w][qloc * 64 + ((((key >> 3) ^ q7) << 3) + (key & 7))] = f2b(sv[nb]);
      }
    }

    #pragma unroll
    for (int kc = 0; kc < 2; ++kc) {
      short8 pa = *(const short8*)&Ps[w][l16 * 64 + (((4 * kc + g) ^ (l16 & 7)) << 3)];
      #pragma unroll
      for (int db = 0; db < 4; ++db) {
        int d = db * 16 + l16;
        short8 bv = *(const short8*)&Vt[d * 64 + (((4 * kc + g) ^ (d & 7)) << 3)];
        o_acc[db] = __builtin_amdgcn_mfma_f32_16x16x32_bf16(pa, bv, o_acc[db], 0, 0, 0);
      }
    }
  }

  #pragma unroll
  for (int r = 0; r < 4; ++r) {
    int qg = r0 + w * 16 + g * 4 + r;
    float inv = 1.0f / lrun[r];
    unsigned short* orow = out + (size_t)qg * DM + h * HD + l16;
    #pragma unroll
    for (int db = 0; db < 4; ++db) orow[db * 16] = f2b(o_acc[db][r] * inv);
  }
}

extern "C" void kernel_launch(void* const* d_in, const int* in_sizes, int n_in,
                              void* d_out, int out_size, void* d_ws, size_t ws_size,
                              hipStream_t stream) {
  const int*   idx   = (const int*)d_in[0];
  const float* embed = (const float*)d_in[1];
  const float* ln1   = (const float*)d_in[2];
  const float* Wq    = (const float*)d_in[3];
  const float* Wk    = (const float*)d_in[4];
  const float* Wv    = (const float*)d_in[5];
  const float* Wo    = (const float*)d_in[6];
  const float* ln2   = (const float*)d_in[7];
  const float* Wg    = (const float*)d_in[8];
  const float* Wu    = (const float*)d_in[9];
  const float* Wd    = (const float*)d_in[10];
  const float* normf = (const float*)d_in[11];
  float* out = (float*)d_out;
  char* ws = (char*)d_ws;
  (void)in_sizes; (void)n_in; (void)out_size; (void)ws_size;

  // ---- workspace layout ----
  unsigned short* embed_bf = (unsigned short*)ws;
  size_t off = (size_t)VOC * DM * 2;
  unsigned short* wts = (unsigned short*)(ws + off);
  const size_t LW = (size_t)QKVN * DM + (size_t)DM * DM
                  + 2ull * FFD * DM + (size_t)DM * FFD;
  off += LW * 2ull * NL;
  float* xf = (float*)(ws + off);            off += (size_t)TSEQ * DM * 4;
  unsigned short* h_bf = (unsigned short*)(ws + off);    off += (size_t)TSEQ * DM * 2;
  unsigned short* qkv_bf = (unsigned short*)(ws + off);  off += (size_t)TSEQ * QKVN * 2;
  unsigned short* attn_bf = (unsigned short*)(ws + off); off += (size_t)TSEQ * DM * 2;
  unsigned short* m_bf = (unsigned short*)(ws + off);    off += (size_t)TSEQ * FFD * 2;

  // ---- prep: embed cast + weight transpose/cast ----
  cast_bf16_kernel<<<(VOC * DM / 4 + 255) / 256, 256, 0, stream>>>(embed, embed_bf, VOC * DM / 4);

  for (int l = 0; l < NL; ++l) {
    unsigned short* base = wts + (size_t)l * LW;
    unsigned short* qkvT = base;
    unsigned short* woT  = base + (size_t)QKVN * DM;
    unsigned short* wguT = woT + (size_t)DM * DM;
    unsigned short* wdT  = wguT + 2ull * FFD * DM;
    transpose_cast_kernel<<<dim3(24, 24), dim3(32, 8), 0, stream>>>(Wq + (size_t)l * 589824, qkvT, 768, 768);
    transpose_cast_kernel<<<dim3(8, 24),  dim3(32, 8), 0, stream>>>(Wk + (size_t)l * 196608, qkvT + 768ull * 768, 768, 256);
    transpose_cast_kernel<<<dim3(8, 24),  dim3(32, 8), 0, stream>>>(Wv + (size_t)l * 196608, qkvT + 1024ull * 768, 768, 256);
    transpose_cast_kernel<<<dim3(24, 24), dim3(32, 8), 0, stream>>>(Wo + (size_t)l * 589824, woT, 768, 768);
    transpose_cast_kernel<<<dim3(64, 24), dim3(32, 8), 0, stream>>>(Wg + (size_t)l * 1572864, wguT, 768, 2048);
    transpose_cast_kernel<<<dim3(64, 24), dim3(32, 8), 0, stream>>>(Wu + (size_t)l * 1572864, wguT + 2048ull * 768, 768, 2048);
    transpose_cast_kernel<<<dim3(24, 64), dim3(32, 8), 0, stream>>>(Wd + (size_t)l * 1572864, wdT, 2048, 768);
  }

  gather_kernel<<<TSEQ, 192, 0, stream>>>(idx, embed, xf);

  for (int l = 0; l < NL; ++l) {
    unsigned short* base = wts + (size_t)l * LW;
    unsigned short* qkvT = base;
    unsigned short* woT  = base + (size_t)QKVN * DM;
    unsigned short* wguT = woT + (size_t)DM * DM;
    unsigned short* wdT  = wguT + 2ull * FFD * DM;

    rmsnorm_kernel<<<TSEQ, 256, 0, stream>>>(xf, ln1 + (size_t)l * DM, h_bf);
    gemm_bt_kernel<2><<<(QKVN / 128) * 16, 256, 0, stream>>>(h_bf, qkvT, qkv_bf, QKVN, DM);
    rope_kernel<<<TSEQ, 256, 0, stream>>>(qkv_bf);
    attn_mfma_kernel<<<dim3(TSEQ / 64, NH), 256, 0, stream>>>(qkv_bf, attn_bf);
    gemm_bt_kernel<1><<<(DM / 128) * 16, 256, 0, stream>>>(attn_bf, woT, xf, DM, DM);
    rmsnorm_kernel<<<TSEQ, 256, 0, stream>>>(xf, ln2 + (size_t)l * DM, h_bf);
    gemm_gu_kernel<<<(FFD / 128) * 16, 256, 0, stream>>>(h_bf, wguT, wguT + (size_t)FFD * DM, m_bf);
    gemm_bt_kernel<1><<<(DM / 128) * 16, 256, 0, stream>>>(m_bf, wdT, xf, DM, FFD);
  }

  rmsnorm_kernel<<<TSEQ, 256, 0, stream>>>(xf, normf, h_bf);
  gemm_bt_kernel<0><<<(VOC / 128) * 16, 256, 0, stream>>>(h_bf, embed_bf, out, VOC, DM);
}